// Round 12
// baseline (231.981 us; speedup 1.0000x reference)
//
#include <hip/hip_runtime.h>
#include <hip/hip_bf16.h>

typedef __bf16 bf16;
typedef bf16 bf16x8 __attribute__((ext_vector_type(8)));
typedef bf16 bf16x4 __attribute__((ext_vector_type(4)));
typedef float f32x4 __attribute__((ext_vector_type(4)));
typedef float f32x16 __attribute__((ext_vector_type(16)));
typedef unsigned int u32;
typedef u32 u32x4 __attribute__((ext_vector_type(4)));

static constexpr int SEQ    = 4096;
static constexpr int DMODEL = 1024;
static constexpr int NHEADS = 16;
static constexpr int DHEAD  = 64;
static constexpr int QKV3   = 3 * DMODEL;  // 3072
static constexpr float SMAX = 64.0f;       // Cauchy-Schwarz bound on q.k after rmsnorm
static constexpr float LOG2E = 1.44269504088896341f;
// R4 lesson: softmax stays exp2(fma(st, LOG2E, -SMAX*LOG2E)) with unscaled q.
// R11 lesson: v_pk_fma_f32/v_pk_add_f32 inline-asm softmax was functionally
// wrong (absmax 3.74) — reverted to the scalar path (R9-proven, 0.0703).

// Async global->LDS 16B copy. LDS dest must be wave-uniform base + lane*16.
__device__ inline void gld16(const bf16* g, bf16* l) {
    __builtin_amdgcn_global_load_lds(
        (const __attribute__((address_space(1))) void*)g,
        (__attribute__((address_space(3))) void*)l, 16, 0, 0);
}

__device__ inline bf16x8 load8(const float* src) {
    float4 a = *(const float4*)(src);
    float4 b = *(const float4*)(src + 4);
    bf16x8 r;
    r[0] = (bf16)a.x; r[1] = (bf16)a.y; r[2] = (bf16)a.z; r[3] = (bf16)a.w;
    r[4] = (bf16)b.x; r[5] = (bf16)b.y; r[6] = (bf16)b.z; r[7] = (bf16)b.w;
    return r;
}

__device__ inline f32x16 zero16() {
    f32x16 r;
#pragma unroll
    for (int i = 0; i < 16; ++i) r[i] = 0.f;
    return r;
}

// ---------------------------------------------------------------------------
static constexpr size_t NX = (size_t)SEQ * DMODEL;     // 4194304
static constexpr size_t NW = (size_t)QKV3 * DMODEL;    // 3145728
static constexpr size_t NO = (size_t)DMODEL * DMODEL;  // 1048576

__global__ __launch_bounds__(256)
void cvt_all(const float* __restrict__ x, const float* __restrict__ Wqkv,
             const float* __restrict__ Wo, bf16* __restrict__ outbase) {
    const size_t e = ((size_t)blockIdx.x * 256 + threadIdx.x) * 8;
    const float* src;
    if (e < NX)            src = x + e;
    else if (e < NX + NW)  src = Wqkv + (e - NX);
    else                   src = Wo + (e - NX - NW);
    *(bf16x8*)(outbase + e) = load8(src);
}

// ---------------------------------------------------------------------------
// QKV GEMM, BK=64 (R9). R12: XCD-chunked block swizzle — bijective remap
// (768 = 8 x 96) so each XCD owns 3 contiguous n-columns; W panel slice
// stays L2-resident across the 32 m-tiles that reuse it. Pure block-id
// permutation: per-block arithmetic identical -> output bit-identical.
// ---------------------------------------------------------------------------
__global__ __launch_bounds__(256)
void gemm_qkv(const bf16* __restrict__ A, const bf16* __restrict__ W,
              const float* __restrict__ bias, const float* __restrict__ wq,
              const float* __restrict__ wk, bf16* __restrict__ qkv,
              bf16* __restrict__ Vt) {
    __shared__ __align__(16) bf16 As[128 * 64];   // 16 KB
    __shared__ __align__(16) bf16 Ws[128 * 64];   // 16 KB
    const int tid  = threadIdx.x;
    const int wave = tid >> 6;
    const int ll   = tid & 15;
    const int quad = (tid & 63) >> 4;
    const int wm   = (wave >> 1) * 64;
    const int wn   = (wave & 1) * 64;
    const int lin  = blockIdx.y * 24 + blockIdx.x;     // 0..767
    const int nlin = (lin & 7) * 96 + (lin >> 3);      // XCD chunk remap
    const int m0 = (nlin & 31) * 128;
    const int n0 = (nlin >> 5) * 128;

    f32x4 acc[4][4];
#pragma unroll
    for (int i = 0; i < 4; ++i)
#pragma unroll
        for (int j = 0; j < 4; ++j) acc[i][j] = (f32x4){0.f, 0.f, 0.f, 0.f};

    for (int k0 = 0; k0 < DMODEL; k0 += 64) {
        __syncthreads();
#pragma unroll
        for (int i = 0; i < 4; ++i) {
            const int idx = i * 256 + tid;          // 0..1023
            const int row = idx >> 3;               // 0..127
            const int c   = (idx & 7) ^ (row & 7);  // 8-chunk XOR swizzle
            gld16(&A[(size_t)(m0 + row) * DMODEL + k0 + c * 8], As + idx * 8);
            gld16(&W[(size_t)(n0 + row) * DMODEL + k0 + c * 8], Ws + idx * 8);
        }
        __syncthreads();
#pragma unroll
        for (int kk = 0; kk < 2; ++kk) {
            bf16x8 af[4], bfr[4];
#pragma unroll
            for (int mi = 0; mi < 4; ++mi) {
                const int row = wm + mi * 16 + ll;
                const int p   = (kk * 4 + quad) ^ (ll & 7);
                af[mi] = *(const bf16x8*)(As + (row * 8 + p) * 8);
            }
#pragma unroll
            for (int ni = 0; ni < 4; ++ni) {
                const int row = wn + ni * 16 + ll;
                const int p   = (kk * 4 + quad) ^ (ll & 7);
                bfr[ni] = *(const bf16x8*)(Ws + (row * 8 + p) * 8);
            }
#pragma unroll
            for (int mi = 0; mi < 4; ++mi)
#pragma unroll
                for (int ni = 0; ni < 4; ++ni)
                    acc[mi][ni] = __builtin_amdgcn_mfma_f32_16x16x32_bf16(
                        af[mi], bfr[ni], acc[mi][ni], 0, 0, 0);
        }
    }

    float bvn[4];
#pragma unroll
    for (int ni = 0; ni < 4; ++ni) bvn[ni] = bias[n0 + wn + ni * 16 + ll];

    const int sect = (n0 + wn) >> 10;      // 0=q, 1=k, 2=v (wave-uniform)
    if (sect < 2) {
        const float* wv = sect ? wk : wq;
        float wvl[4];
#pragma unroll
        for (int ni = 0; ni < 4; ++ni) wvl[ni] = wv[ni * 16 + ll];
#pragma unroll
        for (int mi = 0; mi < 4; ++mi)
#pragma unroll
            for (int r = 0; r < 4; ++r) {
                float xf[4];
                float ss = 0.f;
#pragma unroll
                for (int ni = 0; ni < 4; ++ni) {
                    xf[ni] = (float)(bf16)(acc[mi][ni][r] + bvn[ni]);
                    ss += xf[ni] * xf[ni];
                }
#pragma unroll
                for (int off = 1; off < 16; off <<= 1) ss += __shfl_xor(ss, off);
                const float scale = rsqrtf(ss * (1.0f / 64.0f) + 1e-6f);
                const int row = m0 + wm + mi * 16 + quad * 4 + r;
#pragma unroll
                for (int ni = 0; ni < 4; ++ni)
                    qkv[(size_t)row * QKV3 + n0 + wn + ni * 16 + ll] =
                        (bf16)(xf[ni] * scale * wvl[ni]);
            }
    } else {
        const int h = (n0 + wn - 2 * DMODEL) >> 6;   // head (wave-uniform)
#pragma unroll
        for (int mi = 0; mi < 4; ++mi) {
            const int kv = m0 + wm + mi * 16 + quad * 4;
#pragma unroll
            for (int ni = 0; ni < 4; ++ni) {
                bf16x4 vv;
#pragma unroll
                for (int r = 0; r < 4; ++r) vv[r] = (bf16)(acc[mi][ni][r] + bvn[ni]);
                *(bf16x4*)(Vt + (size_t)(h * DHEAD + ni * 16 + ll) * SEQ + kv) = vv;
            }
        }
    }
}

// ---------------------------------------------------------------------------
// Output GEMM, BK=64 (R9). R12: XCD-chunked swizzle (512 = 8 x 64; bijective).
// ---------------------------------------------------------------------------
__global__ __launch_bounds__(256)
void gemm_out(const bf16* __restrict__ A, const bf16* __restrict__ W,
              const float* __restrict__ bias, float* __restrict__ C) {
    __shared__ __align__(16) bf16 As[128 * 64];   // 16 KB
    __shared__ __align__(16) bf16 Ws[64 * 64];    //  8 KB
    const int tid  = threadIdx.x;
    const int wave = tid >> 6;
    const int ll   = tid & 15;
    const int quad = (tid & 63) >> 4;
    const int lin  = blockIdx.y * 16 + blockIdx.x;     // 0..511
    const int nlin = (lin & 7) * 64 + (lin >> 3);      // XCD chunk remap
    const int m0 = (nlin & 31) * 128;
    const int n0 = (nlin >> 5) * 64;

    f32x4 acc[2][4];
#pragma unroll
    for (int i = 0; i < 2; ++i)
#pragma unroll
        for (int j = 0; j < 4; ++j) acc[i][j] = (f32x4){0.f, 0.f, 0.f, 0.f};

    for (int k0 = 0; k0 < DMODEL; k0 += 64) {
        __syncthreads();
#pragma unroll
        for (int i = 0; i < 4; ++i) {
            const int idx = i * 256 + tid;          // 0..1023
            const int row = idx >> 3;               // 0..127
            const int c   = (idx & 7) ^ (row & 7);
            gld16(&A[(size_t)(m0 + row) * DMODEL + k0 + c * 8], As + idx * 8);
        }
#pragma unroll
        for (int i = 0; i < 2; ++i) {
            const int idx = i * 256 + tid;          // 0..511
            const int row = idx >> 3;               // 0..63
            const int c   = (idx & 7) ^ (row & 7);
            gld16(&W[(size_t)(n0 + row) * DMODEL + k0 + c * 8], Ws + idx * 8);
        }
        __syncthreads();
#pragma unroll
        for (int kk = 0; kk < 2; ++kk) {
            bf16x8 af[2], bfr[4];
#pragma unroll
            for (int mi = 0; mi < 2; ++mi) {
                const int row = wave * 32 + mi * 16 + ll;
                const int p   = (kk * 4 + quad) ^ (ll & 7);
                af[mi] = *(const bf16x8*)(As + (row * 8 + p) * 8);
            }
#pragma unroll
            for (int ni = 0; ni < 4; ++ni) {
                const int row = ni * 16 + ll;
                const int p   = (kk * 4 + quad) ^ (ll & 7);
                bfr[ni] = *(const bf16x8*)(Ws + (row * 8 + p) * 8);
            }
#pragma unroll
            for (int mi = 0; mi < 2; ++mi)
#pragma unroll
                for (int ni = 0; ni < 4; ++ni)
                    acc[mi][ni] = __builtin_amdgcn_mfma_f32_16x16x32_bf16(
                        af[mi], bfr[ni], acc[mi][ni], 0, 0, 0);
        }
    }
#pragma unroll
    for (int ni = 0; ni < 4; ++ni) {
        const int col = n0 + ni * 16 + ll;
        const float bv = bias[col];
#pragma unroll
        for (int mi = 0; mi < 2; ++mi)
#pragma unroll
            for (int r = 0; r < 4; ++r) {
                const int row = m0 + wave * 32 + mi * 16 + quad * 4 + r;
                C[(size_t)row * DMODEL + col] = acc[mi][ni][r] + bv;
            }
    }
}

// ---------------------------------------------------------------------------
// Flash attention: R6/R9-exact structure (session-best, absmax 0.0703).
// 32x32 swapped-operand, dbuf KV prefetch, 64 q-rows/wave, NSPLIT kv split.
// ---------------------------------------------------------------------------
template<int NSPLIT>
__global__ __launch_bounds__(256, 2)
void attn_fwd(const bf16* __restrict__ qkv, const bf16* __restrict__ Vt,
              bf16* __restrict__ z, float* __restrict__ opf,
              float* __restrict__ lsum) {
    constexpr bool PARTIAL = (NSPLIT > 1);
    __shared__ __align__(16) bf16 KV[2][2][64 * 64];   // 32768 B total
    float (*Os)[32][36] = (float(*)[32][36])(&KV[0][0][0]);  // epilogue scratch (18432 B)
    bf16* Qs = &KV[0][0][0];   // prologue Q staging: 256x64 bf16 = 32 KB (whole region)

    const int tid  = threadIdx.x;
    const int wave = tid >> 6;
    const int lane = tid & 63;
    const int l31  = lane & 31;
    const int hh   = lane >> 5;
    const int l7   = lane & 7;
    const int head = blockIdx.x;
    const int q0   = blockIdx.y * 256;
    const int half = PARTIAL ? blockIdx.z : 0;
    const int kvlen = SEQ / NSPLIT;
    const int kvbeg = half * kvlen;
    const int nt    = kvlen / 64;

    const bf16* kbase  = qkv + DMODEL + head * DHEAD;
    const bf16* vtbase = Vt + (size_t)head * DHEAD * SEQ;

    auto stage_kv = [&](int buf, int kv0) {
#pragma unroll
        for (int i = 0; i < 2; ++i) {
            const int idx = i * 256 + tid;
            const int row = idx >> 3;
            const int c   = (idx & 7) ^ (row & 7);
            gld16(kbase + (size_t)(kv0 + row) * QKV3 + c * 8, &KV[buf][0][0] + idx * 8);
            gld16(vtbase + (size_t)row * SEQ + kv0 + c * 8, &KV[buf][1][0] + idx * 8);
        }
    };

    // ---- prologue: stage 256 Q rows into the whole KV region ----
#pragma unroll
    for (int i = 0; i < 8; ++i) {
        const int idx = i * 256 + tid;
        const int row = idx >> 3;
        const int c   = (idx & 7) ^ (row & 7);
        gld16(qkv + (size_t)(q0 + row) * QKV3 + head * DHEAD + c * 8, Qs + idx * 8);
    }
    __syncthreads();
    // Q as B-fragment: n = q = lane&31 (per subtile), k = d = kd*16 + hh*8 + j
    bf16x8 qf[4][2];
#pragma unroll
    for (int kd = 0; kd < 4; ++kd)
#pragma unroll
        for (int qs = 0; qs < 2; ++qs) {
            const int row = wave * 64 + qs * 32 + l31;
            qf[kd][qs] = *(const bf16x8*)(Qs + (row * 8 + ((kd * 2 + hh) ^ l7)) * 8);
        }
    __syncthreads();   // qf reads done before KV staging overwrites region
    stage_kv(0, kvbeg);
    __syncthreads();   // buf0 ready

    f32x16 o[2][2];    // [dt][qs]
    o[0][0] = zero16(); o[0][1] = zero16();
    o[1][0] = zero16(); o[1][1] = zero16();
    float lpa[2][4] = {{0.f, 0.f, 0.f, 0.f}, {0.f, 0.f, 0.f, 0.f}};

    int cur = 0;
    for (int t = 0; t < nt; ++t) {
        if (t + 1 < nt) stage_kv(cur ^ 1, kvbeg + (t + 1) * 64);
        const bf16* Ks  = &KV[cur][0][0];
        const bf16* VTs = &KV[cur][1][0];

#pragma unroll
        for (int kvt = 0; kvt < 2; ++kvt) {
            // S^T tiles for both q-subtiles: each kf read feeds 2 MFMAs.
            f32x16 st0 = zero16(), st1 = zero16();
            __builtin_amdgcn_s_setprio(1);
#pragma unroll
            for (int kd = 0; kd < 4; ++kd) {
                bf16x8 kf = *(const bf16x8*)(
                    Ks + ((kvt * 32 + l31) * 8 + ((kd * 2 + hh) ^ l7)) * 8);
                st0 = __builtin_amdgcn_mfma_f32_32x32x16_bf16(kf, qf[kd][0], st0, 0, 0, 0);
                st1 = __builtin_amdgcn_mfma_f32_32x32x16_bf16(kf, qf[kd][1], st1, 0, 0, 0);
            }
            __builtin_amdgcn_s_setprio(0);

            float pf0[16], pf1[16];
#pragma unroll
            for (int r = 0; r < 16; ++r)
                pf0[r] = __builtin_amdgcn_exp2f(
                    __builtin_fmaf(st0[r], LOG2E, -SMAX * LOG2E));
#pragma unroll
            for (int r = 0; r < 16; ++r)
                pf1[r] = __builtin_amdgcn_exp2f(
                    __builtin_fmaf(st1[r], LOG2E, -SMAX * LOG2E));
#pragma unroll
            for (int r = 0; r < 16; ++r) lpa[0][r & 3] += pf0[r];
#pragma unroll
            for (int r = 0; r < 16; ++r) lpa[1][r & 3] += pf1[r];

            // P^T -> bf16 B-fragments; each vf read feeds 2 MFMAs.
#pragma unroll
            for (int cc = 0; cc < 2; ++cc) {
                u32 a1, b1, a2, b2, a3, b3, a4, b4;
                asm("v_cvt_pk_bf16_f32 %0, %1, %2" : "=v"(a1) : "v"(pf0[8 * cc + 0]), "v"(pf0[8 * cc + 1]));
                asm("v_cvt_pk_bf16_f32 %0, %1, %2" : "=v"(b1) : "v"(pf0[8 * cc + 4]), "v"(pf0[8 * cc + 5]));
                asm("v_cvt_pk_bf16_f32 %0, %1, %2" : "=v"(a2) : "v"(pf0[8 * cc + 2]), "v"(pf0[8 * cc + 3]));
                asm("v_cvt_pk_bf16_f32 %0, %1, %2" : "=v"(b2) : "v"(pf0[8 * cc + 6]), "v"(pf0[8 * cc + 7]));
                asm("v_permlane32_swap_b32 %0, %1" : "+v"(a1), "+v"(b1));
                asm("v_permlane32_swap_b32 %0, %1" : "+v"(a2), "+v"(b2));
                asm("v_cvt_pk_bf16_f32 %0, %1, %2" : "=v"(a3) : "v"(pf1[8 * cc + 0]), "v"(pf1[8 * cc + 1]));
                asm("v_cvt_pk_bf16_f32 %0, %1, %2" : "=v"(b3) : "v"(pf1[8 * cc + 4]), "v"(pf1[8 * cc + 5]));
                asm("v_cvt_pk_bf16_f32 %0, %1, %2" : "=v"(a4) : "v"(pf1[8 * cc + 2]), "v"(pf1[8 * cc + 3]));
                asm("v_cvt_pk_bf16_f32 %0, %1, %2" : "=v"(b4) : "v"(pf1[8 * cc + 6]), "v"(pf1[8 * cc + 7]));
                asm("v_permlane32_swap_b32 %0, %1" : "+v"(a3), "+v"(b3));
                asm("v_permlane32_swap_b32 %0, %1" : "+v"(a4), "+v"(b4));
                u32x4 w0, w1;
                w0[0] = a1; w0[1] = a2; w0[2] = b1; w0[3] = b2;
                w1[0] = a3; w1[1] = a4; w1[2] = b3; w1[3] = b4;
                const bf16x8 bp0 = *(const bf16x8*)&w0;
                const bf16x8 bp1 = *(const bf16x8*)&w1;
                const int c = kvt * 2 + cc;
                __builtin_amdgcn_s_setprio(1);
#pragma unroll
                for (int dt = 0; dt < 2; ++dt) {
                    bf16x8 vf = *(const bf16x8*)(
                        VTs + ((dt * 32 + l31) * 8 + ((c * 2 + hh) ^ l7)) * 8);
                    o[dt][0] = __builtin_amdgcn_mfma_f32_32x32x16_bf16(vf, bp0, o[dt][0], 0, 0, 0);
                    o[dt][1] = __builtin_amdgcn_mfma_f32_32x32x16_bf16(vf, bp1, o[dt][1], 0, 0, 0);
                }
                __builtin_amdgcn_s_setprio(0);
            }
        }
        __syncthreads();   // drains prefetch vmcnt + protects buffer swap
        cur ^= 1;
    }

    // ---- epilogue per q-subtile: O^T -> O via per-wave LDS transpose ----
#pragma unroll
    for (int qs = 0; qs < 2; ++qs) {
        float lp = (lpa[qs][0] + lpa[qs][1]) + (lpa[qs][2] + lpa[qs][3]);
        lp += __shfl_xor(lp, 32);
        const int qrow = q0 + wave * 64 + qs * 32 + l31;
        if (PARTIAL) {
            if (lane < 32) lsum[((size_t)half * SEQ + qrow) * NHEADS + head] = lp;
        }
        const float inv = PARTIAL ? 1.0f : 1.0f / lp;

#pragma unroll
        for (int dt = 0; dt < 2; ++dt) {
#pragma unroll
            for (int r = 0; r < 16; ++r) {
                const int dl = (r & 3) + 8 * (r >> 2) + 4 * hh;   // 0..31
                Os[wave][l31][dl] = o[dt][qs][r] * inv;
            }
#pragma unroll
            for (int it = 0; it < 4; ++it) {
                const int qr  = it * 8 + (lane >> 3);
                const int dl2 = (lane & 7) * 4;
                const f32x4 v = *(const f32x4*)(&Os[wave][qr][dl2]);
                const int row = q0 + wave * 64 + qs * 32 + qr;
                const int col = head * DHEAD + dt * 32 + dl2;
                if (PARTIAL) {
                    *(f32x4*)(opf + ((size_t)half * SEQ + row) * DMODEL + col) = v;
                } else {
                    bf16x4 ov;
                    ov[0] = (bf16)v[0]; ov[1] = (bf16)v[1];
                    ov[2] = (bf16)v[2]; ov[3] = (bf16)v[3];
                    *(bf16x4*)(z + (size_t)row * DMODEL + col) = ov;
                }
            }
        }
    }
}

// ---------------------------------------------------------------------------
// Merge NS KV-split partials: z = (sum o_i)/(sum l_i). One block per q-row.
// ---------------------------------------------------------------------------
template<int NS>
__global__ __launch_bounds__(256)
void combine_halves(const float* __restrict__ opf, const float* __restrict__ lsum,
                    bf16* __restrict__ z) {
    const int row = blockIdx.x;
    const int c   = threadIdx.x * 4;
    const int head = c >> 6;
    float l = 0.f;
#pragma unroll
    for (int s = 0; s < NS; ++s)
        l += lsum[((size_t)s * SEQ + row) * NHEADS + head];
    float4 acc = {0.f, 0.f, 0.f, 0.f};
#pragma unroll
    for (int s = 0; s < NS; ++s) {
        const float4 ov = *(const float4*)(opf + ((size_t)s * SEQ + row) * DMODEL + c);
        acc.x += ov.x; acc.y += ov.y; acc.z += ov.z; acc.w += ov.w;
    }
    bf16x4 out;
    out[0] = (bf16)(acc.x / l);
    out[1] = (bf16)(acc.y / l);
    out[2] = (bf16)(acc.z / l);
    out[3] = (bf16)(acc.w / l);
    *(bf16x4*)(z + (size_t)row * DMODEL + c) = out;
}

// ---------------------------------------------------------------------------
extern "C" void kernel_launch(void* const* d_in, const int* in_sizes, int n_in,
                              void* d_out, int out_size, void* d_ws, size_t ws_size,
                              hipStream_t stream) {
    const float* x    = (const float*)d_in[0];
    const float* Wqkv = (const float*)d_in[1];
    const float* bqkv = (const float*)d_in[2];
    const float* Wo   = (const float*)d_in[3];
    const float* bo   = (const float*)d_in[4];
    const float* wq   = (const float*)d_in[5];
    const float* wk   = (const float*)d_in[6];
    float* out = (float*)d_out;

    bf16* qkv  = (bf16*)d_ws;                       // [4096][3072]  25.2 MB (v third unused)
    bf16* z    = qkv + (size_t)SEQ * QKV3;          // [4096][1024]   8.4 MB
    bf16* Vt   = z + (size_t)SEQ * DMODEL;          // [16][64][4096] 8.4 MB
    bf16* xb   = Vt + (size_t)NHEADS * DHEAD * SEQ; // [4096][1024]   8.4 MB
    bf16* Wqb  = xb + NX;                           // [3072][1024]   6.3 MB
    bf16* Wob  = Wqb + NW;                          // [1024][1024]   2.1 MB
    bf16* endb = Wob + NO;
    float* opf  = (float*)endb;                     // [2][4096][1024] fp32
    float* lsum2 = opf + (size_t)2 * SEQ * DMODEL;
    const size_t need2 = (size_t)((char*)(lsum2 + (size_t)2 * SEQ * NHEADS) - (char*)d_ws);

    cvt_all<<<dim3((NX + NW + NO) / 2048), 256, 0, stream>>>(x, Wqkv, Wo, xb);

    gemm_qkv<<<dim3(QKV3 / 128, SEQ / 128), 256, 0, stream>>>(
        xb, Wqb, bqkv, wq, wk, qkv, Vt);

    if (ws_size >= need2) {
        attn_fwd<2><<<dim3(NHEADS, SEQ / 256, 2), 256, 0, stream>>>(
            qkv, Vt, z, opf, lsum2);
        combine_halves<2><<<dim3(SEQ), 256, 0, stream>>>(opf, lsum2, z);
    } else {
        attn_fwd<1><<<dim3(NHEADS, SEQ / 256, 1), 256, 0, stream>>>(
            qkv, Vt, z, nullptr, nullptr);
    }

    gemm_out<<<dim3(DMODEL / 64, SEQ / 128), 256, 0, stream>>>(z, Wob, bo, out);
}

// Round 13
// 230.459 us; speedup vs baseline: 1.0066x; 1.0066x over previous
//
#include <hip/hip_runtime.h>
#include <hip/hip_bf16.h>

typedef __bf16 bf16;
typedef bf16 bf16x8 __attribute__((ext_vector_type(8)));
typedef bf16 bf16x4 __attribute__((ext_vector_type(4)));
typedef float f32x4 __attribute__((ext_vector_type(4)));
typedef float f32x16 __attribute__((ext_vector_type(16)));
typedef unsigned int u32;
typedef u32 u32x4 __attribute__((ext_vector_type(4)));

static constexpr int SEQ    = 4096;
static constexpr int DMODEL = 1024;
static constexpr int NHEADS = 16;
static constexpr int DHEAD  = 64;
static constexpr int QKV3   = 3 * DMODEL;  // 3072
static constexpr float SMAX = 64.0f;       // Cauchy-Schwarz bound on q.k after rmsnorm
static constexpr float LOG2E = 1.44269504088896341f;
// R4 lesson: softmax stays exp2(fma(st, LOG2E, -SMAX*LOG2E)) with unscaled q.
// R11 lesson: packed-fp32 asm softmax was functionally wrong — scalar path only.
// R12 lesson: GEMM XCD swizzle neutral-to-harmful at K=1024 (panels L3-fit);
// it also perturbed attn's input locality. Reverted.

// Async global->LDS 16B copy. LDS dest must be wave-uniform base + lane*16.
__device__ inline void gld16(const bf16* g, bf16* l) {
    __builtin_amdgcn_global_load_lds(
        (const __attribute__((address_space(1))) void*)g,
        (__attribute__((address_space(3))) void*)l, 16, 0, 0);
}

__device__ inline bf16x8 load8(const float* src) {
    float4 a = *(const float4*)(src);
    float4 b = *(const float4*)(src + 4);
    bf16x8 r;
    r[0] = (bf16)a.x; r[1] = (bf16)a.y; r[2] = (bf16)a.z; r[3] = (bf16)a.w;
    r[4] = (bf16)b.x; r[5] = (bf16)b.y; r[6] = (bf16)b.z; r[7] = (bf16)b.w;
    return r;
}

__device__ inline f32x16 zero16() {
    f32x16 r;
#pragma unroll
    for (int i = 0; i < 16; ++i) r[i] = 0.f;
    return r;
}

// ---------------------------------------------------------------------------
static constexpr size_t NX = (size_t)SEQ * DMODEL;     // 4194304
static constexpr size_t NW = (size_t)QKV3 * DMODEL;    // 3145728
static constexpr size_t NO = (size_t)DMODEL * DMODEL;  // 1048576

__global__ __launch_bounds__(256)
void cvt_all(const float* __restrict__ x, const float* __restrict__ Wqkv,
             const float* __restrict__ Wo, bf16* __restrict__ outbase) {
    const size_t e = ((size_t)blockIdx.x * 256 + threadIdx.x) * 8;
    const float* src;
    if (e < NX)            src = x + e;
    else if (e < NX + NW)  src = Wqkv + (e - NX);
    else                   src = Wo + (e - NX - NW);
    *(bf16x8*)(outbase + e) = load8(src);
}

// ---------------------------------------------------------------------------
// QKV GEMM, BK=64 (R9-exact: no block swizzle).
// ---------------------------------------------------------------------------
__global__ __launch_bounds__(256)
void gemm_qkv(const bf16* __restrict__ A, const bf16* __restrict__ W,
              const float* __restrict__ bias, const float* __restrict__ wq,
              const float* __restrict__ wk, bf16* __restrict__ qkv,
              bf16* __restrict__ Vt) {
    __shared__ __align__(16) bf16 As[128 * 64];   // 16 KB
    __shared__ __align__(16) bf16 Ws[128 * 64];   // 16 KB
    const int tid  = threadIdx.x;
    const int wave = tid >> 6;
    const int ll   = tid & 15;
    const int quad = (tid & 63) >> 4;
    const int wm   = (wave >> 1) * 64;
    const int wn   = (wave & 1) * 64;
    const int m0 = blockIdx.y * 128;
    const int n0 = blockIdx.x * 128;

    f32x4 acc[4][4];
#pragma unroll
    for (int i = 0; i < 4; ++i)
#pragma unroll
        for (int j = 0; j < 4; ++j) acc[i][j] = (f32x4){0.f, 0.f, 0.f, 0.f};

    for (int k0 = 0; k0 < DMODEL; k0 += 64) {
        __syncthreads();
#pragma unroll
        for (int i = 0; i < 4; ++i) {
            const int idx = i * 256 + tid;          // 0..1023
            const int row = idx >> 3;               // 0..127
            const int c   = (idx & 7) ^ (row & 7);  // 8-chunk XOR swizzle
            gld16(&A[(size_t)(m0 + row) * DMODEL + k0 + c * 8], As + idx * 8);
            gld16(&W[(size_t)(n0 + row) * DMODEL + k0 + c * 8], Ws + idx * 8);
        }
        __syncthreads();
#pragma unroll
        for (int kk = 0; kk < 2; ++kk) {
            bf16x8 af[4], bfr[4];
#pragma unroll
            for (int mi = 0; mi < 4; ++mi) {
                const int row = wm + mi * 16 + ll;
                const int p   = (kk * 4 + quad) ^ (ll & 7);
                af[mi] = *(const bf16x8*)(As + (row * 8 + p) * 8);
            }
#pragma unroll
            for (int ni = 0; ni < 4; ++ni) {
                const int row = wn + ni * 16 + ll;
                const int p   = (kk * 4 + quad) ^ (ll & 7);
                bfr[ni] = *(const bf16x8*)(Ws + (row * 8 + p) * 8);
            }
#pragma unroll
            for (int mi = 0; mi < 4; ++mi)
#pragma unroll
                for (int ni = 0; ni < 4; ++ni)
                    acc[mi][ni] = __builtin_amdgcn_mfma_f32_16x16x32_bf16(
                        af[mi], bfr[ni], acc[mi][ni], 0, 0, 0);
        }
    }

    float bvn[4];
#pragma unroll
    for (int ni = 0; ni < 4; ++ni) bvn[ni] = bias[n0 + wn + ni * 16 + ll];

    const int sect = (n0 + wn) >> 10;      // 0=q, 1=k, 2=v (wave-uniform)
    if (sect < 2) {
        const float* wv = sect ? wk : wq;
        float wvl[4];
#pragma unroll
        for (int ni = 0; ni < 4; ++ni) wvl[ni] = wv[ni * 16 + ll];
#pragma unroll
        for (int mi = 0; mi < 4; ++mi)
#pragma unroll
            for (int r = 0; r < 4; ++r) {
                float xf[4];
                float ss = 0.f;
#pragma unroll
                for (int ni = 0; ni < 4; ++ni) {
                    xf[ni] = (float)(bf16)(acc[mi][ni][r] + bvn[ni]);
                    ss += xf[ni] * xf[ni];
                }
#pragma unroll
                for (int off = 1; off < 16; off <<= 1) ss += __shfl_xor(ss, off);
                const float scale = rsqrtf(ss * (1.0f / 64.0f) + 1e-6f);
                const int row = m0 + wm + mi * 16 + quad * 4 + r;
#pragma unroll
                for (int ni = 0; ni < 4; ++ni)
                    qkv[(size_t)row * QKV3 + n0 + wn + ni * 16 + ll] =
                        (bf16)(xf[ni] * scale * wvl[ni]);
            }
    } else {
        const int h = (n0 + wn - 2 * DMODEL) >> 6;   // head (wave-uniform)
#pragma unroll
        for (int mi = 0; mi < 4; ++mi) {
            const int kv = m0 + wm + mi * 16 + quad * 4;
#pragma unroll
            for (int ni = 0; ni < 4; ++ni) {
                bf16x4 vv;
#pragma unroll
                for (int r = 0; r < 4; ++r) vv[r] = (bf16)(acc[mi][ni][r] + bvn[ni]);
                *(bf16x4*)(Vt + (size_t)(h * DHEAD + ni * 16 + ll) * SEQ + kv) = vv;
            }
        }
    }
}

// ---------------------------------------------------------------------------
// Output GEMM, BK=64 (R9-exact: no block swizzle).
// ---------------------------------------------------------------------------
__global__ __launch_bounds__(256)
void gemm_out(const bf16* __restrict__ A, const bf16* __restrict__ W,
              const float* __restrict__ bias, float* __restrict__ C) {
    __shared__ __align__(16) bf16 As[128 * 64];   // 16 KB
    __shared__ __align__(16) bf16 Ws[64 * 64];    //  8 KB
    const int tid  = threadIdx.x;
    const int wave = tid >> 6;
    const int ll   = tid & 15;
    const int quad = (tid & 63) >> 4;
    const int m0 = blockIdx.y * 128;
    const int n0 = blockIdx.x * 64;

    f32x4 acc[2][4];
#pragma unroll
    for (int i = 0; i < 2; ++i)
#pragma unroll
        for (int j = 0; j < 4; ++j) acc[i][j] = (f32x4){0.f, 0.f, 0.f, 0.f};

    for (int k0 = 0; k0 < DMODEL; k0 += 64) {
        __syncthreads();
#pragma unroll
        for (int i = 0; i < 4; ++i) {
            const int idx = i * 256 + tid;          // 0..1023
            const int row = idx >> 3;               // 0..127
            const int c   = (idx & 7) ^ (row & 7);
            gld16(&A[(size_t)(m0 + row) * DMODEL + k0 + c * 8], As + idx * 8);
        }
#pragma unroll
        for (int i = 0; i < 2; ++i) {
            const int idx = i * 256 + tid;          // 0..511
            const int row = idx >> 3;               // 0..63
            const int c   = (idx & 7) ^ (row & 7);
            gld16(&W[(size_t)(n0 + row) * DMODEL + k0 + c * 8], Ws + idx * 8);
        }
        __syncthreads();
#pragma unroll
        for (int kk = 0; kk < 2; ++kk) {
            bf16x8 af[2], bfr[4];
#pragma unroll
            for (int mi = 0; mi < 2; ++mi) {
                const int row = wave * 32 + mi * 16 + ll;
                const int p   = (kk * 4 + quad) ^ (ll & 7);
                af[mi] = *(const bf16x8*)(As + (row * 8 + p) * 8);
            }
#pragma unroll
            for (int ni = 0; ni < 4; ++ni) {
                const int row = ni * 16 + ll;
                const int p   = (kk * 4 + quad) ^ (ll & 7);
                bfr[ni] = *(const bf16x8*)(Ws + (row * 8 + p) * 8);
            }
#pragma unroll
            for (int mi = 0; mi < 2; ++mi)
#pragma unroll
                for (int ni = 0; ni < 4; ++ni)
                    acc[mi][ni] = __builtin_amdgcn_mfma_f32_16x16x32_bf16(
                        af[mi], bfr[ni], acc[mi][ni], 0, 0, 0);
        }
    }
#pragma unroll
    for (int ni = 0; ni < 4; ++ni) {
        const int col = n0 + ni * 16 + ll;
        const float bv = bias[col];
#pragma unroll
        for (int mi = 0; mi < 2; ++mi)
#pragma unroll
            for (int r = 0; r < 4; ++r) {
                const int row = m0 + wave * 32 + mi * 16 + quad * 4 + r;
                C[(size_t)row * DMODEL + col] = acc[mi][ni][r] + bv;
            }
    }
}

// ---------------------------------------------------------------------------
// Flash attention: R9 structure, R13: KVBLK 64->128.
//   - V tile widens to [64 d][128 kv] (16 chunks/row): the `^ (row&15)`
//     swizzle spreads 32 lanes over 16 slots -> 2-way bank access (free,
//     m136), vs the old 8-slot/4-way (1.58x). K tile [128 kv][64 d]
//     unchanged (read pattern requires it; stays 4-way).
//   - One barrier + vmcnt drain per 128 kv instead of 64 (16 vs 32/block).
//   - kv processing order, lpa grouping and all FLOPs preserved ->
//     output bit-identical to R9. LDS 64 KB; 2 blocks/CU unchanged.
// ---------------------------------------------------------------------------
template<int NSPLIT>
__global__ __launch_bounds__(256, 2)
void attn_fwd(const bf16* __restrict__ qkv, const bf16* __restrict__ Vt,
              bf16* __restrict__ z, float* __restrict__ opf,
              float* __restrict__ lsum) {
    constexpr bool PARTIAL = (NSPLIT > 1);
    __shared__ __align__(16) bf16 KV[2][2][128 * 64];  // 65536 B total
    float (*Os)[32][36] = (float(*)[32][36])(&KV[0][0][0]);  // epilogue scratch (18432 B)
    bf16* Qs = &KV[0][0][0];   // prologue Q staging: 256x64 bf16 = 32 KB

    const int tid  = threadIdx.x;
    const int wave = tid >> 6;
    const int lane = tid & 63;
    const int l31  = lane & 31;
    const int hh   = lane >> 5;
    const int l7   = lane & 7;
    const int head = blockIdx.x;
    const int q0   = blockIdx.y * 256;
    const int half = PARTIAL ? blockIdx.z : 0;
    const int kvlen = SEQ / NSPLIT;
    const int kvbeg = half * kvlen;
    const int nt    = kvlen / 128;

    const bf16* kbase  = qkv + DMODEL + head * DHEAD;
    const bf16* vtbase = Vt + (size_t)head * DHEAD * SEQ;

    // K: [128 kv][64 d] rows of 8 chunks, src-swizzled ^(row&7).
    // V: [64 d][128 kv] rows of 16 chunks, src-swizzled ^(row&15).
    auto stage_kv = [&](int buf, int kv0) {
#pragma unroll
        for (int i = 0; i < 4; ++i) {
            const int idx = i * 256 + tid;              // 0..1023
            {
                const int row = idx >> 3;               // 0..127 (kv)
                const int c   = (idx & 7) ^ (row & 7);
                gld16(kbase + (size_t)(kv0 + row) * QKV3 + c * 8,
                      &KV[buf][0][0] + idx * 8);
            }
            {
                const int row = idx >> 4;               // 0..63 (d)
                const int c   = (idx & 15) ^ (row & 15);
                gld16(vtbase + (size_t)row * SEQ + kv0 + c * 8,
                      &KV[buf][1][0] + idx * 8);
            }
        }
    };

    // ---- prologue: stage 256 Q rows into the KV region ----
#pragma unroll
    for (int i = 0; i < 8; ++i) {
        const int idx = i * 256 + tid;
        const int row = idx >> 3;
        const int c   = (idx & 7) ^ (row & 7);
        gld16(qkv + (size_t)(q0 + row) * QKV3 + head * DHEAD + c * 8, Qs + idx * 8);
    }
    __syncthreads();
    // Q as B-fragment: n = q = lane&31 (per subtile), k = d = kd*16 + hh*8 + j
    bf16x8 qf[4][2];
#pragma unroll
    for (int kd = 0; kd < 4; ++kd)
#pragma unroll
        for (int qs = 0; qs < 2; ++qs) {
            const int row = wave * 64 + qs * 32 + l31;
            qf[kd][qs] = *(const bf16x8*)(Qs + (row * 8 + ((kd * 2 + hh) ^ l7)) * 8);
        }
    __syncthreads();   // qf reads done before KV staging overwrites region
    stage_kv(0, kvbeg);
    __syncthreads();   // buf0 ready

    f32x16 o[2][2];    // [dt][qs]
    o[0][0] = zero16(); o[0][1] = zero16();
    o[1][0] = zero16(); o[1][1] = zero16();
    float lpa[2][4] = {{0.f, 0.f, 0.f, 0.f}, {0.f, 0.f, 0.f, 0.f}};

    int cur = 0;
    for (int t = 0; t < nt; ++t) {
        if (t + 1 < nt) stage_kv(cur ^ 1, kvbeg + (t + 1) * 128);
        const bf16* Ks  = &KV[cur][0][0];
        const bf16* VTs = &KV[cur][1][0];

#pragma unroll
        for (int kvt = 0; kvt < 4; ++kvt) {
            // S^T tiles for both q-subtiles: each kf read feeds 2 MFMAs.
            f32x16 st0 = zero16(), st1 = zero16();
            __builtin_amdgcn_s_setprio(1);
#pragma unroll
            for (int kd = 0; kd < 4; ++kd) {
                bf16x8 kf = *(const bf16x8*)(
                    Ks + ((kvt * 32 + l31) * 8 + ((kd * 2 + hh) ^ l7)) * 8);
                st0 = __builtin_amdgcn_mfma_f32_32x32x16_bf16(kf, qf[kd][0], st0, 0, 0, 0);
                st1 = __builtin_amdgcn_mfma_f32_32x32x16_bf16(kf, qf[kd][1], st1, 0, 0, 0);
            }
            __builtin_amdgcn_s_setprio(0);

            float pf0[16], pf1[16];
#pragma unroll
            for (int r = 0; r < 16; ++r)
                pf0[r] = __builtin_amdgcn_exp2f(
                    __builtin_fmaf(st0[r], LOG2E, -SMAX * LOG2E));
#pragma unroll
            for (int r = 0; r < 16; ++r)
                pf1[r] = __builtin_amdgcn_exp2f(
                    __builtin_fmaf(st1[r], LOG2E, -SMAX * LOG2E));
#pragma unroll
            for (int r = 0; r < 16; ++r) lpa[0][r & 3] += pf0[r];
#pragma unroll
            for (int r = 0; r < 16; ++r) lpa[1][r & 3] += pf1[r];

            // P^T -> bf16 B-fragments; each vf read feeds 2 MFMAs.
#pragma unroll
            for (int cc = 0; cc < 2; ++cc) {
                u32 a1, b1, a2, b2, a3, b3, a4, b4;
                asm("v_cvt_pk_bf16_f32 %0, %1, %2" : "=v"(a1) : "v"(pf0[8 * cc + 0]), "v"(pf0[8 * cc + 1]));
                asm("v_cvt_pk_bf16_f32 %0, %1, %2" : "=v"(b1) : "v"(pf0[8 * cc + 4]), "v"(pf0[8 * cc + 5]));
                asm("v_cvt_pk_bf16_f32 %0, %1, %2" : "=v"(a2) : "v"(pf0[8 * cc + 2]), "v"(pf0[8 * cc + 3]));
                asm("v_cvt_pk_bf16_f32 %0, %1, %2" : "=v"(b2) : "v"(pf0[8 * cc + 6]), "v"(pf0[8 * cc + 7]));
                asm("v_permlane32_swap_b32 %0, %1" : "+v"(a1), "+v"(b1));
                asm("v_permlane32_swap_b32 %0, %1" : "+v"(a2), "+v"(b2));
                asm("v_cvt_pk_bf16_f32 %0, %1, %2" : "=v"(a3) : "v"(pf1[8 * cc + 0]), "v"(pf1[8 * cc + 1]));
                asm("v_cvt_pk_bf16_f32 %0, %1, %2" : "=v"(b3) : "v"(pf1[8 * cc + 4]), "v"(pf1[8 * cc + 5]));
                asm("v_cvt_pk_bf16_f32 %0, %1, %2" : "=v"(a4) : "v"(pf1[8 * cc + 2]), "v"(pf1[8 * cc + 3]));
                asm("v_cvt_pk_bf16_f32 %0, %1, %2" : "=v"(b4) : "v"(pf1[8 * cc + 6]), "v"(pf1[8 * cc + 7]));
                asm("v_permlane32_swap_b32 %0, %1" : "+v"(a3), "+v"(b3));
                asm("v_permlane32_swap_b32 %0, %1" : "+v"(a4), "+v"(b4));
                u32x4 w0, w1;
                w0[0] = a1; w0[1] = a2; w0[2] = b1; w0[3] = b2;
                w1[0] = a3; w1[1] = a4; w1[2] = b3; w1[3] = b4;
                const bf16x8 bp0 = *(const bf16x8*)&w0;
                const bf16x8 bp1 = *(const bf16x8*)&w1;
                const int ck = (kvt * 2 + cc) * 2 + hh;   // kv chunk 0..15
                __builtin_amdgcn_s_setprio(1);
#pragma unroll
                for (int dt = 0; dt < 2; ++dt) {
                    const int d = dt * 32 + l31;
                    bf16x8 vf = *(const bf16x8*)(
                        VTs + (d * 16 + (ck ^ (d & 15))) * 8);
                    o[dt][0] = __builtin_amdgcn_mfma_f32_32x32x16_bf16(vf, bp0, o[dt][0], 0, 0, 0);
                    o[dt][1] = __builtin_amdgcn_mfma_f32_32x32x16_bf16(vf, bp1, o[dt][1], 0, 0, 0);
                }
                __builtin_amdgcn_s_setprio(0);
            }
        }
        __syncthreads();   // drains prefetch vmcnt + protects buffer swap
        cur ^= 1;
    }

    // ---- epilogue per q-subtile: O^T -> O via per-wave LDS transpose ----
#pragma unroll
    for (int qs = 0; qs < 2; ++qs) {
        float lp = (lpa[qs][0] + lpa[qs][1]) + (lpa[qs][2] + lpa[qs][3]);
        lp += __shfl_xor(lp, 32);
        const int qrow = q0 + wave * 64 + qs * 32 + l31;
        if (PARTIAL) {
            if (lane < 32) lsum[((size_t)half * SEQ + qrow) * NHEADS + head] = lp;
        }
        const float inv = PARTIAL ? 1.0f : 1.0f / lp;

#pragma unroll
        for (int dt = 0; dt < 2; ++dt) {
#pragma unroll
            for (int r = 0; r < 16; ++r) {
                const int dl = (r & 3) + 8 * (r >> 2) + 4 * hh;   // 0..31
                Os[wave][l31][dl] = o[dt][qs][r] * inv;
            }
#pragma unroll
            for (int it = 0; it < 4; ++it) {
                const int qr  = it * 8 + (lane >> 3);
                const int dl2 = (lane & 7) * 4;
                const f32x4 v = *(const f32x4*)(&Os[wave][qr][dl2]);
                const int row = q0 + wave * 64 + qs * 32 + qr;
                const int col = head * DHEAD + dt * 32 + dl2;
                if (PARTIAL) {
                    *(f32x4*)(opf + ((size_t)half * SEQ + row) * DMODEL + col) = v;
                } else {
                    bf16x4 ov;
                    ov[0] = (bf16)v[0]; ov[1] = (bf16)v[1];
                    ov[2] = (bf16)v[2]; ov[3] = (bf16)v[3];
                    *(bf16x4*)(z + (size_t)row * DMODEL + col) = ov;
                }
            }
        }
    }
}

// ---------------------------------------------------------------------------
// Merge NS KV-split partials: z = (sum o_i)/(sum l_i). One block per q-row.
// ---------------------------------------------------------------------------
template<int NS>
__global__ __launch_bounds__(256)
void combine_halves(const float* __restrict__ opf, const float* __restrict__ lsum,
                    bf16* __restrict__ z) {
    const int row = blockIdx.x;
    const int c   = threadIdx.x * 4;
    const int head = c >> 6;
    float l = 0.f;
#pragma unroll
    for (int s = 0; s < NS; ++s)
        l += lsum[((size_t)s * SEQ + row) * NHEADS + head];
    float4 acc = {0.f, 0.f, 0.f, 0.f};
#pragma unroll
    for (int s = 0; s < NS; ++s) {
        const float4 ov = *(const float4*)(opf + ((size_t)s * SEQ + row) * DMODEL + c);
        acc.x += ov.x; acc.y += ov.y; acc.z += ov.z; acc.w += ov.w;
    }
    bf16x4 out;
    out[0] = (bf16)(acc.x / l);
    out[1] = (bf16)(acc.y / l);
    out[2] = (bf16)(acc.z / l);
    out[3] = (bf16)(acc.w / l);
    *(bf16x4*)(z + (size_t)row * DMODEL + c) = out;
}

// ---------------------------------------------------------------------------
extern "C" void kernel_launch(void* const* d_in, const int* in_sizes, int n_in,
                              void* d_out, int out_size, void* d_ws, size_t ws_size,
                              hipStream_t stream) {
    const float* x    = (const float*)d_in[0];
    const float* Wqkv = (const float*)d_in[1];
    const float* bqkv = (const float*)d_in[2];
    const float* Wo   = (const float*)d_in[3];
    const float* bo   = (const float*)d_in[4];
    const float* wq   = (const float*)d_in[5];
    const float* wk   = (const float*)d_in[6];
    float* out = (float*)d_out;

    bf16* qkv  = (bf16*)d_ws;                       // [4096][3072]  25.2 MB (v third unused)
    bf16* z    = qkv + (size_t)SEQ * QKV3;          // [4096][1024]   8.4 MB
    bf16* Vt   = z + (size_t)SEQ * DMODEL;          // [16][64][4096] 8.4 MB
    bf16* xb   = Vt + (size_t)NHEADS * DHEAD * SEQ; // [4096][1024]   8.4 MB
    bf16* Wqb  = xb + NX;                           // [3072][1024]   6.3 MB
    bf16* Wob  = Wqb + NW;                          // [1024][1024]   2.1 MB
    bf16* endb = Wob + NO;
    float* opf  = (float*)endb;                     // [2][4096][1024] fp32
    float* lsum2 = opf + (size_t)2 * SEQ * DMODEL;
    const size_t need2 = (size_t)((char*)(lsum2 + (size_t)2 * SEQ * NHEADS) - (char*)d_ws);

    cvt_all<<<dim3((NX + NW + NO) / 2048), 256, 0, stream>>>(x, Wqkv, Wo, xb);

    gemm_qkv<<<dim3(QKV3 / 128, SEQ / 128), 256, 0, stream>>>(
        xb, Wqb, bqkv, wq, wk, qkv, Vt);

    if (ws_size >= need2) {
        attn_fwd<2><<<dim3(NHEADS, SEQ / 256, 2), 256, 0, stream>>>(
            qkv, Vt, z, opf, lsum2);
        combine_halves<2><<<dim3(SEQ), 256, 0, stream>>>(opf, lsum2, z);
    } else {
        attn_fwd<1><<<dim3(NHEADS, SEQ / 256, 1), 256, 0, stream>>>(
            qkv, Vt, z, nullptr, nullptr);
    }

    gemm_out<<<dim3(DMODEL / 64, SEQ / 128), 256, 0, stream>>>(z, Wob, bo, out);
}

// Round 14
// 227.583 us; speedup vs baseline: 1.0193x; 1.0126x over previous
//
#include <hip/hip_runtime.h>
#include <hip/hip_bf16.h>

typedef __bf16 bf16;
typedef bf16 bf16x8 __attribute__((ext_vector_type(8)));
typedef bf16 bf16x4 __attribute__((ext_vector_type(4)));
typedef float f32x4 __attribute__((ext_vector_type(4)));
typedef float f32x16 __attribute__((ext_vector_type(16)));
typedef unsigned int u32;
typedef u32 u32x4 __attribute__((ext_vector_type(4)));

static constexpr int SEQ    = 4096;
static constexpr int DMODEL = 1024;
static constexpr int NHEADS = 16;
static constexpr int DHEAD  = 64;
static constexpr int QKV3   = 3 * DMODEL;  // 3072
static constexpr float SMAX = 64.0f;       // Cauchy-Schwarz bound on q.k after rmsnorm
static constexpr float LOG2E = 1.44269504088896341f;
// R4: softmax stays exp2(fma(st, LOG2E, -SMAX*LOG2E)) with unscaled q.
// R11: packed-fp32 asm softmax was wrong — scalar only.
// R12: GEMM XCD swizzle neutral/harmful — no block swizzles.
// R14: gemm_qkv ported to 256x256 8-wave pipelined schedule (raw s_barrier
//      phases, prefetch early + single vmcnt(0) drain per K-tile, setprio
//      around MFMA). Per-output K accumulation order unchanged -> bit-identical.

// Async global->LDS 16B copy. LDS dest must be wave-uniform base + lane*16.
__device__ inline void gld16(const bf16* g, bf16* l) {
    __builtin_amdgcn_global_load_lds(
        (const __attribute__((address_space(1))) void*)g,
        (__attribute__((address_space(3))) void*)l, 16, 0, 0);
}

__device__ inline bf16x8 load8(const float* src) {
    float4 a = *(const float4*)(src);
    float4 b = *(const float4*)(src + 4);
    bf16x8 r;
    r[0] = (bf16)a.x; r[1] = (bf16)a.y; r[2] = (bf16)a.z; r[3] = (bf16)a.w;
    r[4] = (bf16)b.x; r[5] = (bf16)b.y; r[6] = (bf16)b.z; r[7] = (bf16)b.w;
    return r;
}

__device__ inline f32x16 zero16() {
    f32x16 r;
#pragma unroll
    for (int i = 0; i < 16; ++i) r[i] = 0.f;
    return r;
}

// ---------------------------------------------------------------------------
static constexpr size_t NX = (size_t)SEQ * DMODEL;     // 4194304
static constexpr size_t NW = (size_t)QKV3 * DMODEL;    // 3145728
static constexpr size_t NO = (size_t)DMODEL * DMODEL;  // 1048576

__global__ __launch_bounds__(256)
void cvt_all(const float* __restrict__ x, const float* __restrict__ Wqkv,
             const float* __restrict__ Wo, bf16* __restrict__ outbase) {
    const size_t e = ((size_t)blockIdx.x * 256 + threadIdx.x) * 8;
    const float* src;
    if (e < NX)            src = x + e;
    else if (e < NX + NW)  src = Wqkv + (e - NX);
    else                   src = Wo + (e - NX - NW);
    *(bf16x8*)(outbase + e) = load8(src);
}

// ---------------------------------------------------------------------------
// QKV GEMM — R14: 256x256 tile, 8 waves (512 thr), BK=64, double-buffered
// LDS (128 KB), 4 phases/K-tile {ds-reads | prefetch-issue | s_barrier |
// setprio+16 MFMA | s_barrier}, one vmcnt(0) drain per K-tile (prefetch
// issued in phases 0-1, ~3 phases to age). K order per output unchanged.
// ---------------------------------------------------------------------------
__global__ __launch_bounds__(512, 2)
void gemm_qkv(const bf16* __restrict__ A, const bf16* __restrict__ W,
              const float* __restrict__ bias, const float* __restrict__ wq,
              const float* __restrict__ wk, bf16* __restrict__ qkv,
              bf16* __restrict__ Vt) {
    __shared__ __align__(16) bf16 As[2][256 * 64];   // 2 x 32 KB
    __shared__ __align__(16) bf16 Ws[2][256 * 64];   // 2 x 32 KB
    const int tid  = threadIdx.x;        // 0..511
    const int wave = tid >> 6;           // 0..7
    const int lane = tid & 63;
    const int ll   = lane & 15;
    const int quad = lane >> 4;
    const int wr   = wave >> 2;          // 0..1 (m half)
    const int wc   = wave & 3;           // 0..3 (n quarter)
    const int m0 = blockIdx.y * 256;
    const int n0 = blockIdx.x * 256;
    constexpr int NT = DMODEL / 64;      // 16 K-tiles

    f32x4 acc[8][4];
#pragma unroll
    for (int i = 0; i < 8; ++i)
#pragma unroll
        for (int j = 0; j < 4; ++j) acc[i][j] = (f32x4){0.f, 0.f, 0.f, 0.f};

    // Stage half h (j = 2h, 2h+1) of K-tile at k0 into buffer buf.
    auto stage_half = [&](int buf, int k0, int h) {
#pragma unroll
        for (int j = 2 * h; j < 2 * h + 2; ++j) {
            const int idx = j * 512 + tid;          // 0..2047
            const int row = idx >> 3;               // 0..255
            const int c   = (idx & 7) ^ (row & 7);  // 8-chunk XOR swizzle
            gld16(&A[(size_t)(m0 + row) * DMODEL + k0 + c * 8], &As[buf][0] + idx * 8);
            gld16(&W[(size_t)(n0 + row) * DMODEL + k0 + c * 8], &Ws[buf][0] + idx * 8);
        }
    };

    // prologue: stage tile 0, drain, barrier
    stage_half(0, 0, 0);
    stage_half(0, 0, 1);
    asm volatile("s_waitcnt vmcnt(0)" ::: "memory");
    __builtin_amdgcn_s_barrier();

    bf16x8 bfr[4];
    for (int t = 0; t < NT; ++t) {
        const int buf = t & 1;
        const bf16* Ab = &As[buf][0];
        const bf16* Wb = &Ws[buf][0];
#pragma unroll
        for (int ph = 0; ph < 4; ++ph) {
            const int kk = ph >> 1;      // k-half of this K-tile
            const int mh = ph & 1;       // m-half of wave's 128 rows
            // ds-reads for this phase
            bf16x8 af[4];
#pragma unroll
            for (int i = 0; i < 4; ++i) {
                const int row = wr * 128 + (mh * 4 + i) * 16 + ll;
                const int p   = (kk * 4 + quad) ^ (ll & 7);
                af[i] = *(const bf16x8*)(Ab + (row * 8 + p) * 8);
            }
            if (mh == 0) {
#pragma unroll
                for (int ni = 0; ni < 4; ++ni) {
                    const int row = wc * 64 + ni * 16 + ll;
                    const int p   = (kk * 4 + quad) ^ (ll & 7);
                    bfr[ni] = *(const bf16x8*)(Wb + (row * 8 + p) * 8);
                }
            }
            // prefetch next tile (phases 0-1 so loads age before drain)
            if (ph < 2 && t + 1 < NT) stage_half(buf ^ 1, (t + 1) * 64, ph);

            __builtin_amdgcn_s_barrier();
            __builtin_amdgcn_s_setprio(1);
#pragma unroll
            for (int i = 0; i < 4; ++i)
#pragma unroll
                for (int ni = 0; ni < 4; ++ni)
                    acc[mh * 4 + i][ni] = __builtin_amdgcn_mfma_f32_16x16x32_bf16(
                        af[i], bfr[ni], acc[mh * 4 + i][ni], 0, 0, 0);
            __builtin_amdgcn_s_setprio(0);
            if (ph < 3) {
                __builtin_amdgcn_s_barrier();
            } else {
                // tile end: drain own prefetch loads, then barrier
                if (t + 1 < NT) asm volatile("s_waitcnt vmcnt(0)" ::: "memory");
                __builtin_amdgcn_s_barrier();
            }
        }
    }

    // ---- epilogue (same math as R9, 8-wave geometry) ----
    const int ncol0 = n0 + wc * 64;
    float bvn[4];
#pragma unroll
    for (int ni = 0; ni < 4; ++ni) bvn[ni] = bias[ncol0 + ni * 16 + ll];

    const int sect = ncol0 >> 10;      // 0=q, 1=k, 2=v (wave-uniform)
    if (sect < 2) {
        const float* wv = sect ? wk : wq;
        float wvl[4];
#pragma unroll
        for (int ni = 0; ni < 4; ++ni) wvl[ni] = wv[ni * 16 + ll];
#pragma unroll
        for (int mi = 0; mi < 8; ++mi)
#pragma unroll
            for (int r = 0; r < 4; ++r) {
                float xf[4];
                float ss = 0.f;
#pragma unroll
                for (int ni = 0; ni < 4; ++ni) {
                    xf[ni] = (float)(bf16)(acc[mi][ni][r] + bvn[ni]);
                    ss += xf[ni] * xf[ni];
                }
#pragma unroll
                for (int off = 1; off < 16; off <<= 1) ss += __shfl_xor(ss, off);
                const float scale = rsqrtf(ss * (1.0f / 64.0f) + 1e-6f);
                const int row = m0 + wr * 128 + mi * 16 + quad * 4 + r;
#pragma unroll
                for (int ni = 0; ni < 4; ++ni)
                    qkv[(size_t)row * QKV3 + ncol0 + ni * 16 + ll] =
                        (bf16)(xf[ni] * scale * wvl[ni]);
            }
    } else {
        const int h = (ncol0 - 2 * DMODEL) >> 6;   // head (wave-uniform)
#pragma unroll
        for (int mi = 0; mi < 8; ++mi) {
            const int kv = m0 + wr * 128 + mi * 16 + quad * 4;
#pragma unroll
            for (int ni = 0; ni < 4; ++ni) {
                bf16x4 vv;
#pragma unroll
                for (int r = 0; r < 4; ++r) vv[r] = (bf16)(acc[mi][ni][r] + bvn[ni]);
                *(bf16x4*)(Vt + (size_t)(h * DHEAD + ni * 16 + ll) * SEQ + kv) = vv;
            }
        }
    }
}

// ---------------------------------------------------------------------------
// Output GEMM, BK=64 (R9-exact).
// ---------------------------------------------------------------------------
__global__ __launch_bounds__(256)
void gemm_out(const bf16* __restrict__ A, const bf16* __restrict__ W,
              const float* __restrict__ bias, float* __restrict__ C) {
    __shared__ __align__(16) bf16 As[128 * 64];   // 16 KB
    __shared__ __align__(16) bf16 Ws[64 * 64];    //  8 KB
    const int tid  = threadIdx.x;
    const int wave = tid >> 6;
    const int ll   = tid & 15;
    const int quad = (tid & 63) >> 4;
    const int m0 = blockIdx.y * 128;
    const int n0 = blockIdx.x * 64;

    f32x4 acc[2][4];
#pragma unroll
    for (int i = 0; i < 2; ++i)
#pragma unroll
        for (int j = 0; j < 4; ++j) acc[i][j] = (f32x4){0.f, 0.f, 0.f, 0.f};

    for (int k0 = 0; k0 < DMODEL; k0 += 64) {
        __syncthreads();
#pragma unroll
        for (int i = 0; i < 4; ++i) {
            const int idx = i * 256 + tid;          // 0..1023
            const int row = idx >> 3;               // 0..127
            const int c   = (idx & 7) ^ (row & 7);
            gld16(&A[(size_t)(m0 + row) * DMODEL + k0 + c * 8], As + idx * 8);
        }
#pragma unroll
        for (int i = 0; i < 2; ++i) {
            const int idx = i * 256 + tid;          // 0..511
            const int row = idx >> 3;               // 0..63
            const int c   = (idx & 7) ^ (row & 7);
            gld16(&W[(size_t)(n0 + row) * DMODEL + k0 + c * 8], Ws + idx * 8);
        }
        __syncthreads();
#pragma unroll
        for (int kk = 0; kk < 2; ++kk) {
            bf16x8 af[2], bfr[4];
#pragma unroll
            for (int mi = 0; mi < 2; ++mi) {
                const int row = wave * 32 + mi * 16 + ll;
                const int p   = (kk * 4 + quad) ^ (ll & 7);
                af[mi] = *(const bf16x8*)(As + (row * 8 + p) * 8);
            }
#pragma unroll
            for (int ni = 0; ni < 4; ++ni) {
                const int row = ni * 16 + ll;
                const int p   = (kk * 4 + quad) ^ (ll & 7);
                bfr[ni] = *(const bf16x8*)(Ws + (row * 8 + p) * 8);
            }
#pragma unroll
            for (int mi = 0; mi < 2; ++mi)
#pragma unroll
                for (int ni = 0; ni < 4; ++ni)
                    acc[mi][ni] = __builtin_amdgcn_mfma_f32_16x16x32_bf16(
                        af[mi], bfr[ni], acc[mi][ni], 0, 0, 0);
        }
    }
#pragma unroll
    for (int ni = 0; ni < 4; ++ni) {
        const int col = n0 + ni * 16 + ll;
        const float bv = bias[col];
#pragma unroll
        for (int mi = 0; mi < 2; ++mi)
#pragma unroll
            for (int r = 0; r < 4; ++r) {
                const int row = m0 + wave * 32 + mi * 16 + quad * 4 + r;
                C[(size_t)row * DMODEL + col] = acc[mi][ni][r] + bv;
            }
    }
}

// ---------------------------------------------------------------------------
// Flash attention: R13 (KVBLK=128, V 2-way-free swizzle) — unchanged.
// ---------------------------------------------------------------------------
template<int NSPLIT>
__global__ __launch_bounds__(256, 2)
void attn_fwd(const bf16* __restrict__ qkv, const bf16* __restrict__ Vt,
              bf16* __restrict__ z, float* __restrict__ opf,
              float* __restrict__ lsum) {
    constexpr bool PARTIAL = (NSPLIT > 1);
    __shared__ __align__(16) bf16 KV[2][2][128 * 64];  // 65536 B total
    float (*Os)[32][36] = (float(*)[32][36])(&KV[0][0][0]);  // epilogue scratch
    bf16* Qs = &KV[0][0][0];   // prologue Q staging: 256x64 bf16 = 32 KB

    const int tid  = threadIdx.x;
    const int wave = tid >> 6;
    const int lane = tid & 63;
    const int l31  = lane & 31;
    const int hh   = lane >> 5;
    const int l7   = lane & 7;
    const int head = blockIdx.x;
    const int q0   = blockIdx.y * 256;
    const int half = PARTIAL ? blockIdx.z : 0;
    const int kvlen = SEQ / NSPLIT;
    const int kvbeg = half * kvlen;
    const int nt    = kvlen / 128;

    const bf16* kbase  = qkv + DMODEL + head * DHEAD;
    const bf16* vtbase = Vt + (size_t)head * DHEAD * SEQ;

    auto stage_kv = [&](int buf, int kv0) {
#pragma unroll
        for (int i = 0; i < 4; ++i) {
            const int idx = i * 256 + tid;              // 0..1023
            {
                const int row = idx >> 3;               // 0..127 (kv)
                const int c   = (idx & 7) ^ (row & 7);
                gld16(kbase + (size_t)(kv0 + row) * QKV3 + c * 8,
                      &KV[buf][0][0] + idx * 8);
            }
            {
                const int row = idx >> 4;               // 0..63 (d)
                const int c   = (idx & 15) ^ (row & 15);
                gld16(vtbase + (size_t)row * SEQ + kv0 + c * 8,
                      &KV[buf][1][0] + idx * 8);
            }
        }
    };

    // ---- prologue: stage 256 Q rows into the KV region ----
#pragma unroll
    for (int i = 0; i < 8; ++i) {
        const int idx = i * 256 + tid;
        const int row = idx >> 3;
        const int c   = (idx & 7) ^ (row & 7);
        gld16(qkv + (size_t)(q0 + row) * QKV3 + head * DHEAD + c * 8, Qs + idx * 8);
    }
    __syncthreads();
    bf16x8 qf[4][2];
#pragma unroll
    for (int kd = 0; kd < 4; ++kd)
#pragma unroll
        for (int qs = 0; qs < 2; ++qs) {
            const int row = wave * 64 + qs * 32 + l31;
            qf[kd][qs] = *(const bf16x8*)(Qs + (row * 8 + ((kd * 2 + hh) ^ l7)) * 8);
        }
    __syncthreads();
    stage_kv(0, kvbeg);
    __syncthreads();

    f32x16 o[2][2];    // [dt][qs]
    o[0][0] = zero16(); o[0][1] = zero16();
    o[1][0] = zero16(); o[1][1] = zero16();
    float lpa[2][4] = {{0.f, 0.f, 0.f, 0.f}, {0.f, 0.f, 0.f, 0.f}};

    int cur = 0;
    for (int t = 0; t < nt; ++t) {
        if (t + 1 < nt) stage_kv(cur ^ 1, kvbeg + (t + 1) * 128);
        const bf16* Ks  = &KV[cur][0][0];
        const bf16* VTs = &KV[cur][1][0];

#pragma unroll
        for (int kvt = 0; kvt < 4; ++kvt) {
            f32x16 st0 = zero16(), st1 = zero16();
            __builtin_amdgcn_s_setprio(1);
#pragma unroll
            for (int kd = 0; kd < 4; ++kd) {
                bf16x8 kf = *(const bf16x8*)(
                    Ks + ((kvt * 32 + l31) * 8 + ((kd * 2 + hh) ^ l7)) * 8);
                st0 = __builtin_amdgcn_mfma_f32_32x32x16_bf16(kf, qf[kd][0], st0, 0, 0, 0);
                st1 = __builtin_amdgcn_mfma_f32_32x32x16_bf16(kf, qf[kd][1], st1, 0, 0, 0);
            }
            __builtin_amdgcn_s_setprio(0);

            float pf0[16], pf1[16];
#pragma unroll
            for (int r = 0; r < 16; ++r)
                pf0[r] = __builtin_amdgcn_exp2f(
                    __builtin_fmaf(st0[r], LOG2E, -SMAX * LOG2E));
#pragma unroll
            for (int r = 0; r < 16; ++r)
                pf1[r] = __builtin_amdgcn_exp2f(
                    __builtin_fmaf(st1[r], LOG2E, -SMAX * LOG2E));
#pragma unroll
            for (int r = 0; r < 16; ++r) lpa[0][r & 3] += pf0[r];
#pragma unroll
            for (int r = 0; r < 16; ++r) lpa[1][r & 3] += pf1[r];

#pragma unroll
            for (int cc = 0; cc < 2; ++cc) {
                u32 a1, b1, a2, b2, a3, b3, a4, b4;
                asm("v_cvt_pk_bf16_f32 %0, %1, %2" : "=v"(a1) : "v"(pf0[8 * cc + 0]), "v"(pf0[8 * cc + 1]));
                asm("v_cvt_pk_bf16_f32 %0, %1, %2" : "=v"(b1) : "v"(pf0[8 * cc + 4]), "v"(pf0[8 * cc + 5]));
                asm("v_cvt_pk_bf16_f32 %0, %1, %2" : "=v"(a2) : "v"(pf0[8 * cc + 2]), "v"(pf0[8 * cc + 3]));
                asm("v_cvt_pk_bf16_f32 %0, %1, %2" : "=v"(b2) : "v"(pf0[8 * cc + 6]), "v"(pf0[8 * cc + 7]));
                asm("v_permlane32_swap_b32 %0, %1" : "+v"(a1), "+v"(b1));
                asm("v_permlane32_swap_b32 %0, %1" : "+v"(a2), "+v"(b2));
                asm("v_cvt_pk_bf16_f32 %0, %1, %2" : "=v"(a3) : "v"(pf1[8 * cc + 0]), "v"(pf1[8 * cc + 1]));
                asm("v_cvt_pk_bf16_f32 %0, %1, %2" : "=v"(b3) : "v"(pf1[8 * cc + 4]), "v"(pf1[8 * cc + 5]));
                asm("v_cvt_pk_bf16_f32 %0, %1, %2" : "=v"(a4) : "v"(pf1[8 * cc + 2]), "v"(pf1[8 * cc + 3]));
                asm("v_cvt_pk_bf16_f32 %0, %1, %2" : "=v"(b4) : "v"(pf1[8 * cc + 6]), "v"(pf1[8 * cc + 7]));
                asm("v_permlane32_swap_b32 %0, %1" : "+v"(a3), "+v"(b3));
                asm("v_permlane32_swap_b32 %0, %1" : "+v"(a4), "+v"(b4));
                u32x4 w0, w1;
                w0[0] = a1; w0[1] = a2; w0[2] = b1; w0[3] = b2;
                w1[0] = a3; w1[1] = a4; w1[2] = b3; w1[3] = b4;
                const bf16x8 bp0 = *(const bf16x8*)&w0;
                const bf16x8 bp1 = *(const bf16x8*)&w1;
                const int ck = (kvt * 2 + cc) * 2 + hh;   // kv chunk 0..15
                __builtin_amdgcn_s_setprio(1);
#pragma unroll
                for (int dt = 0; dt < 2; ++dt) {
                    const int d = dt * 32 + l31;
                    bf16x8 vf = *(const bf16x8*)(
                        VTs + (d * 16 + (ck ^ (d & 15))) * 8);
                    o[dt][0] = __builtin_amdgcn_mfma_f32_32x32x16_bf16(vf, bp0, o[dt][0], 0, 0, 0);
                    o[dt][1] = __builtin_amdgcn_mfma_f32_32x32x16_bf16(vf, bp1, o[dt][1], 0, 0, 0);
                }
                __builtin_amdgcn_s_setprio(0);
            }
        }
        __syncthreads();
        cur ^= 1;
    }

    // ---- epilogue per q-subtile ----
#pragma unroll
    for (int qs = 0; qs < 2; ++qs) {
        float lp = (lpa[qs][0] + lpa[qs][1]) + (lpa[qs][2] + lpa[qs][3]);
        lp += __shfl_xor(lp, 32);
        const int qrow = q0 + wave * 64 + qs * 32 + l31;
        if (PARTIAL) {
            if (lane < 32) lsum[((size_t)half * SEQ + qrow) * NHEADS + head] = lp;
        }
        const float inv = PARTIAL ? 1.0f : 1.0f / lp;

#pragma unroll
        for (int dt = 0; dt < 2; ++dt) {
#pragma unroll
            for (int r = 0; r < 16; ++r) {
                const int dl = (r & 3) + 8 * (r >> 2) + 4 * hh;   // 0..31
                Os[wave][l31][dl] = o[dt][qs][r] * inv;
            }
#pragma unroll
            for (int it = 0; it < 4; ++it) {
                const int qr  = it * 8 + (lane >> 3);
                const int dl2 = (lane & 7) * 4;
                const f32x4 v = *(const f32x4*)(&Os[wave][qr][dl2]);
                const int row = q0 + wave * 64 + qs * 32 + qr;
                const int col = head * DHEAD + dt * 32 + dl2;
                if (PARTIAL) {
                    *(f32x4*)(opf + ((size_t)half * SEQ + row) * DMODEL + col) = v;
                } else {
                    bf16x4 ov;
                    ov[0] = (bf16)v[0]; ov[1] = (bf16)v[1];
                    ov[2] = (bf16)v[2]; ov[3] = (bf16)v[3];
                    *(bf16x4*)(z + (size_t)row * DMODEL + col) = ov;
                }
            }
        }
    }
}

// ---------------------------------------------------------------------------
template<int NS>
__global__ __launch_bounds__(256)
void combine_halves(const float* __restrict__ opf, const float* __restrict__ lsum,
                    bf16* __restrict__ z) {
    const int row = blockIdx.x;
    const int c   = threadIdx.x * 4;
    const int head = c >> 6;
    float l = 0.f;
#pragma unroll
    for (int s = 0; s < NS; ++s)
        l += lsum[((size_t)s * SEQ + row) * NHEADS + head];
    float4 acc = {0.f, 0.f, 0.f, 0.f};
#pragma unroll
    for (int s = 0; s < NS; ++s) {
        const float4 ov = *(const float4*)(opf + ((size_t)s * SEQ + row) * DMODEL + c);
        acc.x += ov.x; acc.y += ov.y; acc.z += ov.z; acc.w += ov.w;
    }
    bf16x4 out;
    out[0] = (bf16)(acc.x / l);
    out[1] = (bf16)(acc.y / l);
    out[2] = (bf16)(acc.z / l);
    out[3] = (bf16)(acc.w / l);
    *(bf16x4*)(z + (size_t)row * DMODEL + c) = out;
}

// ---------------------------------------------------------------------------
extern "C" void kernel_launch(void* const* d_in, const int* in_sizes, int n_in,
                              void* d_out, int out_size, void* d_ws, size_t ws_size,
                              hipStream_t stream) {
    const float* x    = (const float*)d_in[0];
    const float* Wqkv = (const float*)d_in[1];
    const float* bqkv = (const float*)d_in[2];
    const float* Wo   = (const float*)d_in[3];
    const float* bo   = (const float*)d_in[4];
    const float* wq   = (const float*)d_in[5];
    const float* wk   = (const float*)d_in[6];
    float* out = (float*)d_out;

    bf16* qkv  = (bf16*)d_ws;                       // [4096][3072]  25.2 MB
    bf16* z    = qkv + (size_t)SEQ * QKV3;          // [4096][1024]   8.4 MB
    bf16* Vt   = z + (size_t)SEQ * DMODEL;          // [16][64][4096] 8.4 MB
    bf16* xb   = Vt + (size_t)NHEADS * DHEAD * SEQ; // [4096][1024]   8.4 MB
    bf16* Wqb  = xb + NX;                           // [3072][1024]   6.3 MB
    bf16* Wob  = Wqb + NW;                          // [1024][1024]   2.1 MB
    bf16* endb = Wob + NO;
    float* opf  = (float*)endb;                     // [2][4096][1024] fp32
    float* lsum2 = opf + (size_t)2 * SEQ * DMODEL;
    const size_t need2 = (size_t)((char*)(lsum2 + (size_t)2 * SEQ * NHEADS) - (char*)d_ws);

    cvt_all<<<dim3((NX + NW + NO) / 2048), 256, 0, stream>>>(x, Wqkv, Wo, xb);

    gemm_qkv<<<dim3(QKV3 / 256, SEQ / 256), 512, 0, stream>>>(
        xb, Wqb, bqkv, wq, wk, qkv, Vt);

    if (ws_size >= need2) {
        attn_fwd<2><<<dim3(NHEADS, SEQ / 256, 2), 256, 0, stream>>>(
            qkv, Vt, z, opf, lsum2);
        combine_halves<2><<<dim3(SEQ), 256, 0, stream>>>(opf, lsum2, z);
    } else {
        attn_fwd<1><<<dim3(NHEADS, SEQ / 256, 1), 256, 0, stream>>>(
            qkv, Vt, z, nullptr, nullptr);
    }

    gemm_out<<<dim3(DMODEL / 64, SEQ / 128), 256, 0, stream>>>(z, Wob, bo, out);
}